// Round 2
// baseline (46862.274 us; speedup 1.0000x reference)
//
#include <hip/hip_runtime.h>
#include <hip/hip_cooperative_groups.h>
#include <math.h>

namespace cg = cooperative_groups;

#define B_SZ   32
#define T_SZ   1024
#define IN_SZ  512
#define SEN    512
#define HID    1024
#define MOT    512
#define OUT_SZ 512

#define GBLK   128            // blocks in scan grid
#define JB     (HID / GBLK)   // 8 j-rows per block

// ---------------------------------------------------------------------------
// Generic tiled f32 GEMM:  C[scatter(r), c] = sum_k A[r,k] * op(B)[k,c] + bias[c]
//   TB=true : Bm is [N][K] row-major (computes A @ B^T)
//   TB=false: Bm is [K][N] row-major (computes A @ B)
//   C address for row r, col c:  (r % P)*S1 + (r / P)*S2 + c
// ---------------------------------------------------------------------------
template<bool TB>
__global__ __launch_bounds__(256) void gemm_tiled(
    const float* __restrict__ A, const float* __restrict__ Bm,
    const float* __restrict__ bias, float* __restrict__ C,
    int M, int N, int K, int lda,
    int P, long long S1, long long S2)
{
  __shared__ float As[16][64 + 1];
  __shared__ float Bs[16][64 + 1];
  const int tid = threadIdx.x;
  const int n0 = blockIdx.x * 64;
  const int r0 = blockIdx.y * 64;
  const int ty = tid / 16;
  const int tx = tid % 16;

  float acc[4][4] = {};

  for (int k0 = 0; k0 < K; k0 += 16) {
    {
      const int kk = tid % 16, m0 = tid / 16;
      #pragma unroll
      for (int i = 0; i < 4; i++) {
        const int m = m0 + i * 16;
        As[kk][m] = A[(long long)(r0 + m) * lda + k0 + kk];
      }
    }
    if (TB) {
      const int kk = tid % 16, nl0 = tid / 16;
      #pragma unroll
      for (int i = 0; i < 4; i++) {
        const int n = nl0 + i * 16;
        Bs[kk][n] = Bm[(long long)(n0 + n) * K + k0 + kk];
      }
    } else {
      const int nl = tid % 64, kk0 = tid / 64;
      #pragma unroll
      for (int i = 0; i < 4; i++) {
        const int kk = kk0 + i * 4;
        Bs[kk][nl] = Bm[(long long)(k0 + kk) * N + n0 + nl];
      }
    }
    __syncthreads();

    #pragma unroll
    for (int kk = 0; kk < 16; kk++) {
      float av[4], bv[4];
      #pragma unroll
      for (int i = 0; i < 4; i++) av[i] = As[kk][ty * 4 + i];
      #pragma unroll
      for (int j = 0; j < 4; j++) bv[j] = Bs[kk][tx * 4 + j];
      #pragma unroll
      for (int i = 0; i < 4; i++)
        #pragma unroll
        for (int j = 0; j < 4; j++)
          acc[i][j] += av[i] * bv[j];
    }
    __syncthreads();
  }

  #pragma unroll
  for (int i = 0; i < 4; i++) {
    const int r = r0 + ty * 4 + i;
    const long long base = (long long)(r % P) * S1 + (long long)(r / P) * S2;
    #pragma unroll
    for (int j = 0; j < 4; j++) {
      const int c = n0 + tx * 4 + j;
      float v = acc[i][j];
      if (bias) v += bias[c];
      C[base + c] = v;
    }
  }
}

// bias_eff[h] = b_cell[h] + dot(W_x[h,:], b_in)
__global__ void bias_eff_kernel(const float* __restrict__ Wx,
                                const float* __restrict__ b_in,
                                const float* __restrict__ b_cell,
                                float* __restrict__ bias_eff)
{
  const int h = blockIdx.x * 256 + threadIdx.x;
  float s = b_cell[h];
  for (int k = 0; k < SEN; k++) s += Wx[h * SEN + k] * b_in[k];
  bias_eff[h] = s;
}

// ---------------------------------------------------------------------------
// Persistent cooperative scan: all 1024 steps in one kernel, grid.sync/step.
// Block bk owns j-rows [bk*JB, bk*JB+JB); W_h slice lives in LDS (padded rows
// so the 8 distinct per-wave ds_read_b128 addresses hit distinct banks).
// Thread = (b = tid>>3, jl = tid&7) computes one (b,j) output per step.
// h double-buffered in global ws; __threadfence (agent release: wbl2+inv)
// before grid.sync makes cross-XCD h writes visible.
// ---------------------------------------------------------------------------
__global__ __launch_bounds__(256) void scan_kernel(
    const float* __restrict__ init_h,
    const float* __restrict__ Wh,
    const float* __restrict__ pre,        // [T][B][HID]
    const float* __restrict__ timespans,  // [B][T]
    const float* __restrict__ Avec,
    const float* __restrict__ tau,
    float* __restrict__ hseq,             // [T][B][MOT]
    float* __restrict__ hb0,
    float* __restrict__ hb1)
{
  __shared__ float WhS[JB][HID + 4];   // +4 pad: row stride 1028 -> distinct banks
  const int tid = threadIdx.x;
  const int b   = tid >> 3;
  const int jl  = tid & 7;
  const int j   = blockIdx.x * JB + jl;

  // stage W_h slice into LDS (coalesced float4)
  for (int r = 0; r < JB; r++) {
    const float4* src = (const float4*)(Wh + ((size_t)blockIdx.x * JB + r) * HID);
    float4* dst = (float4*)&WhS[r][0];
    for (int idx = tid; idx < HID / 4; idx += 256) dst[idx] = src[idx];
  }
  const float a_j  = Avec[j];
  const float it_j = 1.f / tau[j];
  const float* tsb = timespans + b * T_SZ;
  __syncthreads();

  cg::grid_group grid = cg::this_grid();

  for (int t = 0; t < T_SZ; t++) {
    const float* hsrc = (t == 0) ? init_h : ((t & 1) ? hb1 : hb0);
    float* hdst = (t & 1) ? hb0 : hb1;

    const float4* hp = (const float4*)(hsrc + b * HID);
    const float4* wp = (const float4*)&WhS[jl][0];

    float acc = 0.f;
    #pragma unroll 8
    for (int k = 0; k < HID / 4; k++) {
      const float4 hv = hp[k];
      const float4 wv = wp[k];
      acc = fmaf(hv.x, wv.x, acc);
      acc = fmaf(hv.y, wv.y, acc);
      acc = fmaf(hv.z, wv.z, acc);
      acc = fmaf(hv.w, wv.w, acc);
    }

    const float z  = acc + pre[(size_t)t * B_SZ * HID + b * HID + j];
    const float f  = 1.f / (1.f + expf(-z));
    const float ts = tsb[t];
    const float h0 = hsrc[b * HID + j];
    const float hn = (h0 + ts * f * a_j) / (1.f + ts * (it_j + f));

    hdst[b * HID + j] = hn;
    if (j < MOT) hseq[(size_t)t * B_SZ * MOT + b * MOT + j] = hn;

    __threadfence();   // agent-scope release (wbl2) + inv for next step's reads
    grid.sync();
  }
}

extern "C" void kernel_launch(void* const* d_in, const int* in_sizes, int n_in,
                              void* d_out, int out_size, void* d_ws, size_t ws_size,
                              hipStream_t stream)
{
  const float* inputs    = (const float*)d_in[0];
  const float* timespans = (const float*)d_in[1];
  const float* init_h    = (const float*)d_in[2];
  const float* W_in      = (const float*)d_in[3];
  const float* b_in      = (const float*)d_in[4];
  const float* W_x       = (const float*)d_in[5];
  const float* W_h       = (const float*)d_in[6];
  const float* b_cell    = (const float*)d_in[7];
  const float* tau       = (const float*)d_in[8];
  const float* A         = (const float*)d_in[9];
  const float* W_out     = (const float*)d_in[10];
  const float* b_out     = (const float*)d_in[11];
  float* out = (float*)d_out;

  float* ws    = (float*)d_ws;
  float* pre   = ws;                                  // T*B*HID
  float* hseq  = pre   + (size_t)T_SZ * B_SZ * HID;   // T*B*MOT
  float* Wxi   = hseq  + (size_t)T_SZ * B_SZ * MOT;   // HID*IN_SZ
  float* beff  = Wxi   + (size_t)HID * IN_SZ;         // HID
  float* hbuf0 = beff  + HID;                         // B*HID
  float* hbuf1 = hbuf0 + (size_t)B_SZ * HID;          // B*HID

  // K0: Wxi = W_x @ W_in
  gemm_tiled<false><<<dim3(IN_SZ / 64, HID / 64), 256, 0, stream>>>(
      W_x, W_in, nullptr, Wxi, HID, IN_SZ, SEN, SEN,
      1 << 30, (long long)IN_SZ, 0LL);

  bias_eff_kernel<<<HID / 256, 256, 0, stream>>>(W_x, b_in, b_cell, beff);

  // K1: pre[t][b][h] = inputs[r=b*T+t,:] @ Wxi^T + beff
  gemm_tiled<true><<<dim3(HID / 64, (B_SZ * T_SZ) / 64), 256, 0, stream>>>(
      inputs, Wxi, beff, pre, B_SZ * T_SZ, HID, IN_SZ, IN_SZ,
      T_SZ, (long long)B_SZ * HID, (long long)HID);

  // K2: persistent cooperative scan (one dispatch, 1024 grid.sync steps)
  {
    void* args[] = {
      (void*)&init_h, (void*)&W_h, (void*)&pre, (void*)&timespans,
      (void*)&A, (void*)&tau, (void*)&hseq, (void*)&hbuf0, (void*)&hbuf1
    };
    hipLaunchCooperativeKernel((void*)scan_kernel, dim3(GBLK), dim3(256),
                               args, 0, stream);
  }

  // K3: out[b][t][o] = hseq[r=t*B+b, :MOT] @ W_out^T + b_out
  gemm_tiled<true><<<dim3(OUT_SZ / 64, (B_SZ * T_SZ) / 64), 256, 0, stream>>>(
      hseq, W_out, b_out, out, B_SZ * T_SZ, OUT_SZ, MOT, MOT,
      B_SZ, (long long)T_SZ * OUT_SZ, (long long)OUT_SZ);

  // last_state: t=1023 (odd) wrote hbuf0
  hipMemcpyAsync(out + (size_t)B_SZ * T_SZ * OUT_SZ, hbuf0,
                 (size_t)B_SZ * HID * sizeof(float),
                 hipMemcpyDeviceToDevice, stream);
}

// Round 3
// 44997.037 us; speedup vs baseline: 1.0415x; 1.0415x over previous
//
#include <hip/hip_runtime.h>
#include <math.h>

#define B_SZ   32
#define T_SZ   1024
#define IN_SZ  512
#define SEN    512
#define HID    1024
#define MOT    512
#define OUT_SZ 512

// ---------------------------------------------------------------------------
// Generic tiled f32 GEMM:  C[scatter(r), c] = sum_k A[r,k] * op(B)[k,c] + bias[c]
//   TB=true : Bm is [N][K] row-major (computes A @ B^T)
//   TB=false: Bm is [K][N] row-major (computes A @ B)
//   C address for row r, col c:  (r % P)*S1 + (r / P)*S2 + c
// ---------------------------------------------------------------------------
template<bool TB>
__global__ __launch_bounds__(256) void gemm_tiled(
    const float* __restrict__ A, const float* __restrict__ Bm,
    const float* __restrict__ bias, float* __restrict__ C,
    int M, int N, int K, int lda,
    int P, long long S1, long long S2)
{
  __shared__ float As[16][64 + 1];
  __shared__ float Bs[16][64 + 1];
  const int tid = threadIdx.x;
  const int n0 = blockIdx.x * 64;
  const int r0 = blockIdx.y * 64;
  const int ty = tid / 16;
  const int tx = tid % 16;

  float acc[4][4] = {};

  for (int k0 = 0; k0 < K; k0 += 16) {
    {
      const int kk = tid % 16, m0 = tid / 16;
      #pragma unroll
      for (int i = 0; i < 4; i++) {
        const int m = m0 + i * 16;
        As[kk][m] = A[(long long)(r0 + m) * lda + k0 + kk];
      }
    }
    if (TB) {
      const int kk = tid % 16, nl0 = tid / 16;
      #pragma unroll
      for (int i = 0; i < 4; i++) {
        const int n = nl0 + i * 16;
        Bs[kk][n] = Bm[(long long)(n0 + n) * K + k0 + kk];
      }
    } else {
      const int nl = tid % 64, kk0 = tid / 64;
      #pragma unroll
      for (int i = 0; i < 4; i++) {
        const int kk = kk0 + i * 4;
        Bs[kk][nl] = Bm[(long long)(k0 + kk) * N + n0 + nl];
      }
    }
    __syncthreads();

    #pragma unroll
    for (int kk = 0; kk < 16; kk++) {
      float av[4], bv[4];
      #pragma unroll
      for (int i = 0; i < 4; i++) av[i] = As[kk][ty * 4 + i];
      #pragma unroll
      for (int j = 0; j < 4; j++) bv[j] = Bs[kk][tx * 4 + j];
      #pragma unroll
      for (int i = 0; i < 4; i++)
        #pragma unroll
        for (int j = 0; j < 4; j++)
          acc[i][j] += av[i] * bv[j];
    }
    __syncthreads();
  }

  #pragma unroll
  for (int i = 0; i < 4; i++) {
    const int r = r0 + ty * 4 + i;
    const long long base = (long long)(r % P) * S1 + (long long)(r / P) * S2;
    #pragma unroll
    for (int j = 0; j < 4; j++) {
      const int c = n0 + tx * 4 + j;
      float v = acc[i][j];
      if (bias) v += bias[c];
      C[base + c] = v;
    }
  }
}

// bias_eff[h] = b_cell[h] + dot(W_x[h,:], b_in)
__global__ void bias_eff_kernel(const float* __restrict__ Wx,
                                const float* __restrict__ b_in,
                                const float* __restrict__ b_cell,
                                float* __restrict__ bias_eff)
{
  const int h = blockIdx.x * 256 + threadIdx.x;
  float s = b_cell[h];
  for (int k = 0; k < SEN; k++) s += Wx[h * SEN + k] * b_in[k];
  bias_eff[h] = s;
}

// ---------------------------------------------------------------------------
// Pack + transpose W_h (f32 [HID][HID]) -> Wp (bf16x2 dwords, [HID/2][HID]):
//   Wp[k2][j] = ( bf16(W_h[j][2*k2+1]) << 16 ) | bf16(W_h[j][2*k2])
// so that lane j reads coalesced dwords and unpacks two f32 weights.
// ---------------------------------------------------------------------------
__device__ inline uint32_t f2bf_rne(float x) {
  const uint32_t u = __float_as_uint(x);
  return (u + 0x7fffu + ((u >> 16) & 1u)) >> 16;   // round-to-nearest-even
}

__global__ __launch_bounds__(256) void pack_wh_kernel(
    const float* __restrict__ Wh, uint32_t* __restrict__ Wp)
{
  __shared__ float tile[64][65];
  const int j0 = blockIdx.x * 64;
  const int k0 = blockIdx.y * 64;
  const int c  = threadIdx.x & 63;
  const int r0 = threadIdx.x >> 6;   // 0..3
  #pragma unroll
  for (int i = 0; i < 16; ++i) {
    const int r = r0 + i * 4;
    tile[r][c] = Wh[(size_t)(j0 + r) * HID + k0 + c];   // coalesced over c
  }
  __syncthreads();
  #pragma unroll
  for (int p = 0; p < 8; ++p) {
    const int idx = p * 256 + threadIdx.x;
    const int k2l = idx >> 6;        // 0..31
    const int jl  = idx & 63;
    const uint32_t lo = f2bf_rne(tile[jl][2 * k2l]);
    const uint32_t hi = f2bf_rne(tile[jl][2 * k2l + 1]);
    Wp[(size_t)(k0 / 2 + k2l) * HID + j0 + jl] = (hi << 16) | lo;  // coalesced over jl
  }
}

// ---------------------------------------------------------------------------
// Per-batch-element scan: block b runs ALL 1024 steps for batch element b.
// Zero cross-block communication -> no device-wide sync at all.
// Thread j owns h[b,j] (in register); block-local h mirror in global memory
// (hbuf[b]) read via wave-uniform float4 loads; W_h streamed from L2 as
// packed bf16x2 coalesced dwords (2 MB/step/CU — the VMEM-return wall).
// Per-step sync: __syncthreads x2 + __threadfence_block (workgroup scope).
// ---------------------------------------------------------------------------
__global__ __launch_bounds__(1024) void scan_b_kernel(
    const float* __restrict__ init_h,
    const uint32_t* __restrict__ Wp,      // [HID/2][HID] packed bf16x2
    const float* __restrict__ pre,        // [T][B][HID]
    const float* __restrict__ timespans,  // [B][T]
    const float* __restrict__ Avec,
    const float* __restrict__ tau,
    float* __restrict__ hseq,             // [T][B][MOT]
    float* __restrict__ hbuf,             // [B][HID] scratch
    float* __restrict__ last_state)       // [B][HID] (points into d_out)
{
  const int b = blockIdx.x;
  const int j = threadIdx.x;
  float* hb = hbuf + (size_t)b * HID;

  float h_reg = init_h[b * HID + j];
  hb[j] = h_reg;
  const float a_j  = Avec[j];
  const float it_j = 1.f / tau[j];

  __threadfence_block();   // h stores visible to the block
  __syncthreads();

  const float4* h4 = (const float4*)hb;

  for (int t = 0; t < T_SZ; ++t) {
    const float prev = pre[(size_t)t * (B_SZ * HID) + b * HID + j];
    const float ts   = timespans[b * T_SZ + t];

    float acc0 = 0.f, acc1 = 0.f, acc2 = 0.f, acc3 = 0.f;
    const uint32_t* wp = Wp + j;
    #pragma unroll 8
    for (int k4 = 0; k4 < HID / 4; ++k4) {
      const float4  hv = h4[k4];                       // wave-uniform (16B/fetch)
      const uint32_t w0 = wp[(size_t)(2 * k4 + 0) * HID];  // coalesced dword
      const uint32_t w1 = wp[(size_t)(2 * k4 + 1) * HID];
      acc0 = fmaf(__uint_as_float(w0 << 16),         hv.x, acc0);
      acc1 = fmaf(__uint_as_float(w0 & 0xffff0000u), hv.y, acc1);
      acc2 = fmaf(__uint_as_float(w1 << 16),         hv.z, acc2);
      acc3 = fmaf(__uint_as_float(w1 & 0xffff0000u), hv.w, acc3);
    }
    const float z  = (acc0 + acc1) + (acc2 + acc3) + prev;
    const float f  = 1.f / (1.f + __expf(-z));
    const float hn = (h_reg + ts * f * a_j) / (1.f + ts * (it_j + f));

    __syncthreads();            // everyone finished reading h for this step
    h_reg = hn;
    hb[j] = hn;
    if (j < MOT) hseq[(size_t)t * (B_SZ * MOT) + b * MOT + j] = hn;
    __threadfence_block();      // vmcnt(0): stores visible before next dot
    __syncthreads();
  }

  last_state[b * HID + j] = h_reg;
}

extern "C" void kernel_launch(void* const* d_in, const int* in_sizes, int n_in,
                              void* d_out, int out_size, void* d_ws, size_t ws_size,
                              hipStream_t stream)
{
  const float* inputs    = (const float*)d_in[0];
  const float* timespans = (const float*)d_in[1];
  const float* init_h    = (const float*)d_in[2];
  const float* W_in      = (const float*)d_in[3];
  const float* b_in      = (const float*)d_in[4];
  const float* W_x       = (const float*)d_in[5];
  const float* W_h       = (const float*)d_in[6];
  const float* b_cell    = (const float*)d_in[7];
  const float* tau       = (const float*)d_in[8];
  const float* A         = (const float*)d_in[9];
  const float* W_out     = (const float*)d_in[10];
  const float* b_out     = (const float*)d_in[11];
  float* out = (float*)d_out;

  float* ws    = (float*)d_ws;
  float* pre   = ws;                                  // T*B*HID   f32
  float* hseq  = pre   + (size_t)T_SZ * B_SZ * HID;   // T*B*MOT   f32
  float* WxiWp = hseq  + (size_t)T_SZ * B_SZ * MOT;   // HID*IN_SZ (Wxi, then reused as Wp)
  float* beff  = WxiWp + (size_t)HID * IN_SZ;         // HID
  float* hbuf  = beff  + HID;                         // B*HID

  // K0: Wxi = W_x @ W_in   (folds the input projection into the cell GEMM)
  gemm_tiled<false><<<dim3(IN_SZ / 64, HID / 64), 256, 0, stream>>>(
      W_x, W_in, nullptr, WxiWp, HID, IN_SZ, SEN, SEN,
      1 << 30, (long long)IN_SZ, 0LL);

  bias_eff_kernel<<<HID / 256, 256, 0, stream>>>(W_x, b_in, b_cell, beff);

  // K1: pre[t][b][h] = inputs[r=b*T+t,:] @ Wxi^T + beff
  gemm_tiled<true><<<dim3(HID / 64, (B_SZ * T_SZ) / 64), 256, 0, stream>>>(
      inputs, WxiWp, beff, pre, B_SZ * T_SZ, HID, IN_SZ, IN_SZ,
      T_SZ, (long long)B_SZ * HID, (long long)HID);

  // K2a: pack/transpose W_h -> bf16x2 (reuses the Wxi slot; runs after K1)
  pack_wh_kernel<<<dim3(HID / 64, HID / 64), 256, 0, stream>>>(
      W_h, (uint32_t*)WxiWp);

  // K2b: the scan — 32 independent blocks, one per batch element
  scan_b_kernel<<<B_SZ, 1024, 0, stream>>>(
      init_h, (const uint32_t*)WxiWp, pre, timespans, A, tau,
      hseq, hbuf, out + (size_t)B_SZ * T_SZ * OUT_SZ);

  // K3: out[b][t][o] = hseq[r=t*B+b, :MOT] @ W_out^T + b_out
  gemm_tiled<true><<<dim3(OUT_SZ / 64, (B_SZ * T_SZ) / 64), 256, 0, stream>>>(
      hseq, W_out, b_out, out, B_SZ * T_SZ, OUT_SZ, MOT, MOT,
      B_SZ, (long long)T_SZ * OUT_SZ, (long long)OUT_SZ);
}

// Round 5
// 12472.166 us; speedup vs baseline: 3.7573x; 3.6078x over previous
//
#include <hip/hip_runtime.h>
#include <math.h>

#define B_SZ   32
#define T_SZ   1024
#define IN_SZ  512
#define SEN    512
#define HID    1024
#define MOT    512
#define OUT_SZ 512

#define NBLK   32          // scan blocks (j-slices)
#define JSL    32          // j's per block
#define K2     512         // f16-pair words per h row
#define HPAD   516         // padded h_lds row stride (dwords)

typedef __fp16 h2_t __attribute__((ext_vector_type(2)));

__device__ inline float fd2(uint32_t a, uint32_t b, float c) {
  h2_t ha = __builtin_bit_cast(h2_t, a);
  h2_t hb = __builtin_bit_cast(h2_t, b);
  return __builtin_amdgcn_fdot2(ha, hb, c, false);
}

__device__ inline uint32_t pk16(float a, float b) {
  auto p = __builtin_amdgcn_cvt_pkrtz(a, b);
  return __builtin_bit_cast(uint32_t, p);
}

// ---------------------------------------------------------------------------
// Generic tiled f32 GEMM:  C[scatter(r), c] = sum_k A[r,k] * op(B)[k,c] + bias[c]
//   TB=true : Bm is [N][K] row-major (A @ B^T);  TB=false: Bm is [K][N] (A @ B)
//   C address for row r, col c:  (r % P)*S1 + (r / P)*S2 + c
// ---------------------------------------------------------------------------
template<bool TB>
__global__ __launch_bounds__(256) void gemm_tiled(
    const float* __restrict__ A, const float* __restrict__ Bm,
    const float* __restrict__ bias, float* __restrict__ C,
    int M, int N, int K, int lda,
    int P, long long S1, long long S2)
{
  __shared__ float As[16][64 + 1];
  __shared__ float Bs[16][64 + 1];
  const int tid = threadIdx.x;
  const int n0 = blockIdx.x * 64;
  const int r0 = blockIdx.y * 64;
  const int ty = tid / 16;
  const int tx = tid % 16;

  float acc[4][4] = {};

  for (int k0 = 0; k0 < K; k0 += 16) {
    {
      const int kk = tid % 16, m0 = tid / 16;
      #pragma unroll
      for (int i = 0; i < 4; i++) {
        const int m = m0 + i * 16;
        As[kk][m] = A[(long long)(r0 + m) * lda + k0 + kk];
      }
    }
    if (TB) {
      const int kk = tid % 16, nl0 = tid / 16;
      #pragma unroll
      for (int i = 0; i < 4; i++) {
        const int n = nl0 + i * 16;
        Bs[kk][n] = Bm[(long long)(n0 + n) * K + k0 + kk];
      }
    } else {
      const int nl = tid % 64, kk0 = tid / 64;
      #pragma unroll
      for (int i = 0; i < 4; i++) {
        const int kk = kk0 + i * 4;
        Bs[kk][nl] = Bm[(long long)(k0 + kk) * N + n0 + nl];
      }
    }
    __syncthreads();

    #pragma unroll
    for (int kk = 0; kk < 16; kk++) {
      float av[4], bv[4];
      #pragma unroll
      for (int i = 0; i < 4; i++) av[i] = As[kk][ty * 4 + i];
      #pragma unroll
      for (int j = 0; j < 4; j++) bv[j] = Bs[kk][tx * 4 + j];
      #pragma unroll
      for (int i = 0; i < 4; i++)
        #pragma unroll
        for (int j = 0; j < 4; j++)
          acc[i][j] += av[i] * bv[j];
    }
    __syncthreads();
  }

  #pragma unroll
  for (int i = 0; i < 4; i++) {
    const int r = r0 + ty * 4 + i;
    const long long base = (long long)(r % P) * S1 + (long long)(r / P) * S2;
    #pragma unroll
    for (int j = 0; j < 4; j++) {
      const int c = n0 + tx * 4 + j;
      float v = acc[i][j];
      if (bias) v += bias[c];
      C[base + c] = v;
    }
  }
}

// bias_eff[h] = b_cell[h] + dot(W_x[h,:], b_in)
__global__ void bias_eff_kernel(const float* __restrict__ Wx,
                                const float* __restrict__ b_in,
                                const float* __restrict__ b_cell,
                                float* __restrict__ bias_eff)
{
  const int h = blockIdx.x * 256 + threadIdx.x;
  float s = b_cell[h];
  for (int k = 0; k < SEN; k++) s += Wx[h * SEN + k] * b_in[k];
  bias_eff[h] = s;
}

// Pack W_h f32 [j][k] -> Wp16 u32 [j][k2]: pack(f16(W[j][2k2]), f16(W[j][2k2+1]))
__global__ __launch_bounds__(256) void pack_wh16_kernel(
    const float* __restrict__ Wh, uint32_t* __restrict__ Wp16)
{
  const int idx = blockIdx.x * 256 + threadIdx.x;       // j*K2 + k2
  const float2 v = *(const float2*)(Wh + (size_t)idx * 2);
  Wp16[idx] = pk16(v.x, v.y);
}

// ---------------------------------------------------------------------------
// Scan v3: 32 blocks x 512 threads. Block bk owns j in [bk*32, bk*32+32) for
// ALL 32 batch elements; its W_h slice (f16x2, 64 KB) lives in LDS for the
// whole scan. h state (all 1024 j, f16x2 per b) mirrored in LDS (pad-516
// rows). Per step: fdot2 dots -> liquid update -> publish own h dwords via
// agent-scope atomics -> lean global barrier -> re-import h.
// Thread: b = tid&31, jg = tid>>5 (j0 = bk*32 + 2*jg, j1 = j0+1).
// ---------------------------------------------------------------------------
__global__ __launch_bounds__(512) void scan_x_kernel(
    const float* __restrict__ init_h,
    const uint32_t* __restrict__ Wp16,   // [HID][K2]
    const float* __restrict__ pre,       // [T][B][HID]
    const float* __restrict__ tsp,       // [B][T]
    const float* __restrict__ Avec,
    const float* __restrict__ tau,
    float* __restrict__ hseq,            // [T][B][MOT]
    uint32_t* __restrict__ hx,           // [2][B][K2] exchange
    uint32_t* __restrict__ cnt,          // barrier counter (pre-zeroed)
    float* __restrict__ last_state)      // [B][HID]
{
  __shared__ uint32_t w_lds[JSL * K2];     // 64 KB
  __shared__ uint32_t h_lds[B_SZ * HPAD];  // 66 KB

  const int bk  = blockIdx.x;
  const int tid = threadIdx.x;
  const int b   = tid & 31;
  const int jg  = tid >> 5;                // 0..15
  const int j0  = bk * JSL + 2 * jg;

  // stage weight slice (once)
  {
    const uint32_t* src = Wp16 + (size_t)bk * JSL * K2;
    for (int i = tid; i < JSL * K2; i += 512) w_lds[i] = src[i];
  }
  // stage initial h (f32 -> f16x2)
  for (int i = tid; i < B_SZ * K2; i += 512) {
    const int bb = i >> 9, k2 = i & (K2 - 1);
    const float2 v = *(const float2*)(init_h + bb * HID + 2 * k2);
    h_lds[bb * HPAD + k2] = pk16(v.x, v.y);
  }

  const float2 apair = *(const float2*)(Avec + j0);
  const float2 tpair = *(const float2*)(tau + j0);
  const float it0 = 1.f / tpair.x, it1 = 1.f / tpair.y;
  float2 hreg = *(const float2*)(init_h + b * HID + j0);

  __syncthreads();

  const uint32_t* hrow  = &h_lds[b * HPAD];
  const uint32_t* wrow0 = &w_lds[(2 * jg) * K2];
  const uint32_t* wrow1 = &w_lds[(2 * jg + 1) * K2];

  for (int t = 0; t < T_SZ; ++t) {
    const float2 prev = *(const float2*)(pre + (size_t)t * (B_SZ * HID) + b * HID + j0);
    const float  ts   = tsp[b * T_SZ + t];

    float a00 = 0.f, a01 = 0.f, a10 = 0.f, a11 = 0.f;
    #pragma unroll 4
    for (int c = 0; c < K2 / 4; ++c) {
      const uint4 hv = *(const uint4*)(hrow + 4 * c);
      const uint4 w0 = *(const uint4*)(wrow0 + 4 * c);   // uniform per half-wave
      const uint4 w1 = *(const uint4*)(wrow1 + 4 * c);
      a00 = fd2(hv.x, w0.x, a00); a01 = fd2(hv.y, w0.y, a01);
      a00 = fd2(hv.z, w0.z, a00); a01 = fd2(hv.w, w0.w, a01);
      a10 = fd2(hv.x, w1.x, a10); a11 = fd2(hv.y, w1.y, a11);
      a10 = fd2(hv.z, w1.z, a10); a11 = fd2(hv.w, w1.w, a11);
    }
    const float z0 = (a00 + a01) + prev.x;
    const float z1 = (a10 + a11) + prev.y;
    const float f0 = 1.f / (1.f + __expf(-z0));
    const float f1 = 1.f / (1.f + __expf(-z1));
    const float hn0 = (hreg.x + ts * f0 * apair.x) / (1.f + ts * (it0 + f0));
    const float hn1 = (hreg.y + ts * f1 * apair.y) / (1.f + ts * (it1 + f1));
    hreg.x = hn0; hreg.y = hn1;

    // publish own h dword (agent scope -> coherence point)
    uint32_t* hxw = hx + ((t + 1) & 1) * (B_SZ * K2);
    __hip_atomic_store(&hxw[b * K2 + bk * (JSL / 2) + jg], pk16(hn0, hn1),
                       __ATOMIC_RELAXED, __HIP_MEMORY_SCOPE_AGENT);
    if (bk < 16) {  // motor half -> hseq (f32)
      *(float2*)(hseq + (size_t)t * (B_SZ * MOT) + b * MOT + j0) = make_float2(hn0, hn1);
    }

    __syncthreads();   // all dots done reading h_lds; stores drained

    if (tid == 0) {
      __hip_atomic_fetch_add(cnt, 1u, __ATOMIC_RELEASE, __HIP_MEMORY_SCOPE_AGENT);
      const uint32_t target = (uint32_t)NBLK * (uint32_t)(t + 1);
      while (__hip_atomic_load(cnt, __ATOMIC_RELAXED, __HIP_MEMORY_SCOPE_AGENT) < target)
        __builtin_amdgcn_s_sleep(1);
      __scoped_atomic_thread_fence(__ATOMIC_ACQUIRE, __MEMORY_SCOPE_DEVICE);  // inv stale lines
    }
    __syncthreads();

    // re-import full h state
    {
      const uint32_t* hxr = hx + ((t + 1) & 1) * (B_SZ * K2);
      #pragma unroll
      for (int p = 0; p < 8; ++p) {
        const int q = tid + p * 512;           // uint4 chunk id, 4096 total
        const uint4 g = *(const uint4*)(hxr + 4 * q);
        *(uint4*)&h_lds[(q >> 7) * HPAD + 4 * (q & 127)] = g;
      }
    }
    __syncthreads();
  }

  *(float2*)(last_state + b * HID + j0) = hreg;
}

extern "C" void kernel_launch(void* const* d_in, const int* in_sizes, int n_in,
                              void* d_out, int out_size, void* d_ws, size_t ws_size,
                              hipStream_t stream)
{
  const float* inputs    = (const float*)d_in[0];
  const float* timespans = (const float*)d_in[1];
  const float* init_h    = (const float*)d_in[2];
  const float* W_in      = (const float*)d_in[3];
  const float* b_in      = (const float*)d_in[4];
  const float* W_x       = (const float*)d_in[5];
  const float* W_h       = (const float*)d_in[6];
  const float* b_cell    = (const float*)d_in[7];
  const float* tau       = (const float*)d_in[8];
  const float* A         = (const float*)d_in[9];
  const float* W_out     = (const float*)d_in[10];
  const float* b_out     = (const float*)d_in[11];
  float* out = (float*)d_out;

  float*    ws    = (float*)d_ws;
  float*    pre   = ws;                                  // T*B*HID f32
  float*    hseq  = pre   + (size_t)T_SZ * B_SZ * HID;   // T*B*MOT f32
  float*    WxiWp = hseq  + (size_t)T_SZ * B_SZ * MOT;   // HID*IN_SZ (Wxi f32, then Wp16 u32)
  float*    beff  = WxiWp + (size_t)HID * IN_SZ;         // HID
  uint32_t* hx    = (uint32_t*)(beff + HID);             // 2*B*K2
  uint32_t* cnt   = hx + 2 * B_SZ * K2;                  // 16 u32

  // K0: Wxi = W_x @ W_in  (fold input projection into cell GEMM)
  gemm_tiled<false><<<dim3(IN_SZ / 64, HID / 64), 256, 0, stream>>>(
      W_x, W_in, nullptr, WxiWp, HID, IN_SZ, SEN, SEN,
      1 << 30, (long long)IN_SZ, 0LL);

  bias_eff_kernel<<<HID / 256, 256, 0, stream>>>(W_x, b_in, b_cell, beff);

  // K1: pre[t][b][h] = inputs[r=b*T+t,:] @ Wxi^T + beff
  gemm_tiled<true><<<dim3(HID / 64, (B_SZ * T_SZ) / 64), 256, 0, stream>>>(
      inputs, WxiWp, beff, pre, B_SZ * T_SZ, HID, IN_SZ, IN_SZ,
      T_SZ, (long long)B_SZ * HID, (long long)HID);

  // K2a: pack W_h -> f16x2 (overwrites Wxi slot; stream order makes it safe)
  pack_wh16_kernel<<<(HID * K2) / 256, 256, 0, stream>>>(W_h, (uint32_t*)WxiWp);

  // K2b: zero barrier counter (re-zeroed every replay)
  (void)hipMemsetAsync(cnt, 0, 64, stream);

  // K2c: the scan — cooperative launch guarantees co-residency of 32 blocks
  {
    const uint32_t* Wp16c = (const uint32_t*)WxiWp;
    float* last_state = out + (size_t)B_SZ * T_SZ * OUT_SZ;
    void* args[] = {
      (void*)&init_h, (void*)&Wp16c, (void*)&pre, (void*)&timespans,
      (void*)&A, (void*)&tau, (void*)&hseq, (void*)&hx, (void*)&cnt,
      (void*)&last_state
    };
    (void)hipLaunchCooperativeKernel((void*)scan_x_kernel, dim3(NBLK), dim3(512),
                                     args, 0, stream);
  }

  // K3: out[b][t][o] = hseq[r=t*B+b, :MOT] @ W_out^T + b_out
  gemm_tiled<true><<<dim3(OUT_SZ / 64, (B_SZ * T_SZ) / 64), 256, 0, stream>>>(
      hseq, W_out, b_out, out, B_SZ * T_SZ, OUT_SZ, MOT, MOT,
      B_SZ, (long long)T_SZ * OUT_SZ, (long long)OUT_SZ);
}

// Round 6
// 11495.258 us; speedup vs baseline: 4.0767x; 1.0850x over previous
//
#include <hip/hip_runtime.h>
#include <math.h>

#define B_SZ   32
#define T_SZ   1024
#define IN_SZ  512
#define SEN    512
#define HID    1024
#define MOT    512
#define OUT_SZ 512

#define NBLK   32          // scan blocks (j-slices)
#define JSL    32          // j's per block
#define K2     512         // f16-pair words per h row
#define HPAD   516         // padded h_lds row stride (dwords)

typedef __fp16 h2_t __attribute__((ext_vector_type(2)));

__device__ inline float fd2(uint32_t a, uint32_t b, float c) {
  h2_t ha = __builtin_bit_cast(h2_t, a);
  h2_t hb = __builtin_bit_cast(h2_t, b);
  return __builtin_amdgcn_fdot2(ha, hb, c, false);
}

__device__ inline uint32_t pk16(float a, float b) {
  auto p = __builtin_amdgcn_cvt_pkrtz(a, b);
  return __builtin_bit_cast(uint32_t, p);
}

// ---------------------------------------------------------------------------
// Generic tiled f32 GEMM:  C[scatter(r), c] = sum_k A[r,k] * op(B)[k,c] + bias[c]
//   TB=true : Bm is [N][K] row-major (A @ B^T);  TB=false: Bm is [K][N] (A @ B)
//   C address for row r, col c:  (r % P)*S1 + (r / P)*S2 + c
// ---------------------------------------------------------------------------
template<bool TB>
__global__ __launch_bounds__(256) void gemm_tiled(
    const float* __restrict__ A, const float* __restrict__ Bm,
    const float* __restrict__ bias, float* __restrict__ C,
    int M, int N, int K, int lda,
    int P, long long S1, long long S2)
{
  __shared__ float As[16][64 + 1];
  __shared__ float Bs[16][64 + 1];
  const int tid = threadIdx.x;
  const int n0 = blockIdx.x * 64;
  const int r0 = blockIdx.y * 64;
  const int ty = tid / 16;
  const int tx = tid % 16;

  float acc[4][4] = {};

  for (int k0 = 0; k0 < K; k0 += 16) {
    {
      const int kk = tid % 16, m0 = tid / 16;
      #pragma unroll
      for (int i = 0; i < 4; i++) {
        const int m = m0 + i * 16;
        As[kk][m] = A[(long long)(r0 + m) * lda + k0 + kk];
      }
    }
    if (TB) {
      const int kk = tid % 16, nl0 = tid / 16;
      #pragma unroll
      for (int i = 0; i < 4; i++) {
        const int n = nl0 + i * 16;
        Bs[kk][n] = Bm[(long long)(n0 + n) * K + k0 + kk];
      }
    } else {
      const int nl = tid % 64, kk0 = tid / 64;
      #pragma unroll
      for (int i = 0; i < 4; i++) {
        const int kk = kk0 + i * 4;
        Bs[kk][nl] = Bm[(long long)(k0 + kk) * N + n0 + nl];
      }
    }
    __syncthreads();

    #pragma unroll
    for (int kk = 0; kk < 16; kk++) {
      float av[4], bv[4];
      #pragma unroll
      for (int i = 0; i < 4; i++) av[i] = As[kk][ty * 4 + i];
      #pragma unroll
      for (int j = 0; j < 4; j++) bv[j] = Bs[kk][tx * 4 + j];
      #pragma unroll
      for (int i = 0; i < 4; i++)
        #pragma unroll
        for (int j = 0; j < 4; j++)
          acc[i][j] += av[i] * bv[j];
    }
    __syncthreads();
  }

  #pragma unroll
  for (int i = 0; i < 4; i++) {
    const int r = r0 + ty * 4 + i;
    const long long base = (long long)(r % P) * S1 + (long long)(r / P) * S2;
    #pragma unroll
    for (int j = 0; j < 4; j++) {
      const int c = n0 + tx * 4 + j;
      float v = acc[i][j];
      if (bias) v += bias[c];
      C[base + c] = v;
    }
  }
}

// bias_eff[h] = b_cell[h] + dot(W_x[h,:], b_in)
__global__ void bias_eff_kernel(const float* __restrict__ Wx,
                                const float* __restrict__ b_in,
                                const float* __restrict__ b_cell,
                                float* __restrict__ bias_eff)
{
  const int h = blockIdx.x * 256 + threadIdx.x;
  float s = b_cell[h];
  for (int k = 0; k < SEN; k++) s += Wx[h * SEN + k] * b_in[k];
  bias_eff[h] = s;
}

// Pack W_h f32 [j][k] -> Wp16 u32 [j][k2]: pack(f16(W[j][2k2]), f16(W[j][2k2+1]))
__global__ __launch_bounds__(256) void pack_wh16_kernel(
    const float* __restrict__ Wh, uint32_t* __restrict__ Wp16)
{
  const int idx = blockIdx.x * 256 + threadIdx.x;       // j*K2 + k2
  const float2 v = *(const float2*)(Wh + (size_t)idx * 2);
  Wp16[idx] = pk16(v.x, v.y);
}

// ---------------------------------------------------------------------------
// Scan v4: 32 blocks x 512 threads, j-sliced, W_h slice resident in LDS.
// Lean barrier protocol (no cache-wide fences):
//   - hx writes: device-scope relaxed atomic stores (write-through to the
//     coherence point; drained by __syncthreads' vmcnt(0))
//   - arrival: RELAXED fetch_add (no release -> no buffer_wbl2)
//   - NO acquire fence; re-import reads hx via device-scope relaxed atomic
//     64-bit loads (per-access coherent, caches stay warm for pre/w)
//   - pre[t+1]/ts[t+1] prefetched into registers before the barrier wait
// ---------------------------------------------------------------------------
__global__ __launch_bounds__(512) void scan_x_kernel(
    const float* __restrict__ init_h,
    const uint32_t* __restrict__ Wp16,   // [HID][K2]
    const float* __restrict__ pre,       // [T][B][HID]
    const float* __restrict__ tsp,       // [B][T]
    const float* __restrict__ Avec,
    const float* __restrict__ tau,
    float* __restrict__ hseq,            // [T][B][MOT]
    uint32_t* __restrict__ hx,           // [2][B][K2] exchange
    uint32_t* __restrict__ cnt,          // barrier counter (pre-zeroed)
    float* __restrict__ last_state)      // [B][HID]
{
  __shared__ uint32_t w_lds[JSL * K2];     // 64 KB
  __shared__ uint32_t h_lds[B_SZ * HPAD];  // 66 KB

  const int bk  = blockIdx.x;
  const int tid = threadIdx.x;
  const int b   = tid & 31;
  const int jg  = tid >> 5;                // 0..15
  const int j0  = bk * JSL + 2 * jg;

  // stage weight slice (once)
  {
    const uint32_t* src = Wp16 + (size_t)bk * JSL * K2;
    for (int i = tid; i < JSL * K2; i += 512) w_lds[i] = src[i];
  }
  // stage initial h (f32 -> f16x2)
  for (int i = tid; i < B_SZ * K2; i += 512) {
    const int bb = i >> 9, k2 = i & (K2 - 1);
    const float2 v = *(const float2*)(init_h + bb * HID + 2 * k2);
    h_lds[bb * HPAD + k2] = pk16(v.x, v.y);
  }

  const float2 apair = *(const float2*)(Avec + j0);
  const float2 tpair = *(const float2*)(tau + j0);
  const float it0 = 1.f / tpair.x, it1 = 1.f / tpair.y;
  float2 hreg = *(const float2*)(init_h + b * HID + j0);

  __syncthreads();

  const uint32_t* hrow  = &h_lds[b * HPAD];
  const uint32_t* wrow0 = &w_lds[(2 * jg) * K2];
  const uint32_t* wrow1 = &w_lds[(2 * jg + 1) * K2];

  // prefetch step-0 inputs
  float2 prevC = *(const float2*)(pre + (size_t)0 + b * HID + j0);
  float  tsC   = tsp[b * T_SZ + 0];

  for (int t = 0; t < T_SZ; ++t) {
    float a00 = 0.f, a01 = 0.f, a10 = 0.f, a11 = 0.f;
    #pragma unroll 4
    for (int c = 0; c < K2 / 4; ++c) {
      const uint4 hv = *(const uint4*)(hrow + 4 * c);
      const uint4 w0 = *(const uint4*)(wrow0 + 4 * c);   // uniform per half-wave
      const uint4 w1 = *(const uint4*)(wrow1 + 4 * c);
      a00 = fd2(hv.x, w0.x, a00); a01 = fd2(hv.y, w0.y, a01);
      a00 = fd2(hv.z, w0.z, a00); a01 = fd2(hv.w, w0.w, a01);
      a10 = fd2(hv.x, w1.x, a10); a11 = fd2(hv.y, w1.y, a11);
      a10 = fd2(hv.z, w1.z, a10); a11 = fd2(hv.w, w1.w, a11);
    }
    const float z0 = (a00 + a01) + prevC.x;
    const float z1 = (a10 + a11) + prevC.y;
    const float f0 = 1.f / (1.f + __expf(-z0));
    const float f1 = 1.f / (1.f + __expf(-z1));
    const float hn0 = (hreg.x + tsC * f0 * apair.x) / (1.f + tsC * (it0 + f0));
    const float hn1 = (hreg.y + tsC * f1 * apair.y) / (1.f + tsC * (it1 + f1));
    hreg.x = hn0; hreg.y = hn1;

    // publish own h dword (device-scope write-through; drained by syncthreads)
    uint32_t* hxw = hx + ((t + 1) & 1) * (B_SZ * K2);
    __hip_atomic_store(&hxw[b * K2 + bk * (JSL / 2) + jg], pk16(hn0, hn1),
                       __ATOMIC_RELAXED, __HIP_MEMORY_SCOPE_AGENT);
    if (bk < 16) {  // motor half -> hseq (f32)
      *(float2*)(hseq + (size_t)t * (B_SZ * MOT) + b * MOT + j0) = make_float2(hn0, hn1);
    }

    // prefetch next step's pre/ts while stores drain / barrier settles
    const int tn = (t + 1 < T_SZ) ? t + 1 : t;
    prevC = *(const float2*)(pre + (size_t)tn * (B_SZ * HID) + b * HID + j0);
    tsC   = tsp[b * T_SZ + tn];

    __syncthreads();   // drains vmcnt(0): hx stores globally visible

    if (tid == 0) {
      __hip_atomic_fetch_add(cnt, 1u, __ATOMIC_RELAXED, __HIP_MEMORY_SCOPE_AGENT);
      const uint32_t target = (uint32_t)NBLK * (uint32_t)(t + 1);
      while (__hip_atomic_load(cnt, __ATOMIC_RELAXED, __HIP_MEMORY_SCOPE_AGENT) < target)
        __builtin_amdgcn_s_sleep(1);
    }
    __syncthreads();

    // re-import full h state via device-scope coherent 8B loads
    {
      const unsigned long long* hxr =
          (const unsigned long long*)(hx + ((t + 1) & 1) * (B_SZ * K2));
      unsigned long long v[16];
      #pragma unroll
      for (int p = 0; p < 16; ++p)
        v[p] = __hip_atomic_load(&hxr[tid + p * 512],
                                 __ATOMIC_RELAXED, __HIP_MEMORY_SCOPE_AGENT);
      #pragma unroll
      for (int p = 0; p < 16; ++p) {
        const int q  = tid + p * 512;          // uint2 chunk id, 8192 total
        const int bb = q >> 8;                 // 256 chunks per b-row
        const int k2 = (q & 255) * 2;
        *(uint2*)&h_lds[bb * HPAD + k2] = make_uint2((uint32_t)v[p],
                                                     (uint32_t)(v[p] >> 32));
      }
    }
    __syncthreads();
  }

  *(float2*)(last_state + b * HID + j0) = hreg;
}

extern "C" void kernel_launch(void* const* d_in, const int* in_sizes, int n_in,
                              void* d_out, int out_size, void* d_ws, size_t ws_size,
                              hipStream_t stream)
{
  const float* inputs    = (const float*)d_in[0];
  const float* timespans = (const float*)d_in[1];
  const float* init_h    = (const float*)d_in[2];
  const float* W_in      = (const float*)d_in[3];
  const float* b_in      = (const float*)d_in[4];
  const float* W_x       = (const float*)d_in[5];
  const float* W_h       = (const float*)d_in[6];
  const float* b_cell    = (const float*)d_in[7];
  const float* tau       = (const float*)d_in[8];
  const float* A         = (const float*)d_in[9];
  const float* W_out     = (const float*)d_in[10];
  const float* b_out     = (const float*)d_in[11];
  float* out = (float*)d_out;

  float*    ws    = (float*)d_ws;
  float*    pre   = ws;                                  // T*B*HID f32
  float*    hseq  = pre   + (size_t)T_SZ * B_SZ * HID;   // T*B*MOT f32
  float*    WxiWp = hseq  + (size_t)T_SZ * B_SZ * MOT;   // HID*IN_SZ (Wxi f32, then Wp16 u32)
  float*    beff  = WxiWp + (size_t)HID * IN_SZ;         // HID
  uint32_t* hx    = (uint32_t*)(beff + HID);             // 2*B*K2
  uint32_t* cnt   = hx + 2 * B_SZ * K2;                  // 16 u32

  // K0: Wxi = W_x @ W_in  (fold input projection into cell GEMM)
  gemm_tiled<false><<<dim3(IN_SZ / 64, HID / 64), 256, 0, stream>>>(
      W_x, W_in, nullptr, WxiWp, HID, IN_SZ, SEN, SEN,
      1 << 30, (long long)IN_SZ, 0LL);

  bias_eff_kernel<<<HID / 256, 256, 0, stream>>>(W_x, b_in, b_cell, beff);

  // K1: pre[t][b][h] = inputs[r=b*T+t,:] @ Wxi^T + beff
  gemm_tiled<true><<<dim3(HID / 64, (B_SZ * T_SZ) / 64), 256, 0, stream>>>(
      inputs, WxiWp, beff, pre, B_SZ * T_SZ, HID, IN_SZ, IN_SZ,
      T_SZ, (long long)B_SZ * HID, (long long)HID);

  // K2a: pack W_h -> f16x2 (overwrites Wxi slot; stream order makes it safe)
  pack_wh16_kernel<<<(HID * K2) / 256, 256, 0, stream>>>(W_h, (uint32_t*)WxiWp);

  // K2b: zero barrier counter (re-zeroed every replay)
  (void)hipMemsetAsync(cnt, 0, 64, stream);

  // K2c: the scan — cooperative launch guarantees co-residency of 32 blocks
  {
    const uint32_t* Wp16c = (const uint32_t*)WxiWp;
    float* last_state = out + (size_t)B_SZ * T_SZ * OUT_SZ;
    void* args[] = {
      (void*)&init_h, (void*)&Wp16c, (void*)&pre, (void*)&timespans,
      (void*)&A, (void*)&tau, (void*)&hseq, (void*)&hx, (void*)&cnt,
      (void*)&last_state
    };
    (void)hipLaunchCooperativeKernel((void*)scan_x_kernel, dim3(NBLK), dim3(512),
                                     args, 0, stream);
  }

  // K3: out[b][t][o] = hseq[r=t*B+b, :MOT] @ W_out^T + b_out
  gemm_tiled<true><<<dim3(OUT_SZ / 64, (B_SZ * T_SZ) / 64), 256, 0, stream>>>(
      hseq, W_out, b_out, out, B_SZ * T_SZ, OUT_SZ, MOT, MOT,
      B_SZ, (long long)T_SZ * OUT_SZ, (long long)OUT_SZ);
}